// Round 5
// baseline (62765.173 us; speedup 1.0000x reference)
//
#include <hip/hip_runtime.h>

#define DI __device__ __forceinline__

// ---------------- workspace layout (4-byte element offsets) ----------------
enum : int {
  OFF_XYZF = 0,                          // [4][8192][3] f32 (z = pipe*2+b)
  OFF_FEAF = OFF_XYZF + 4*8192*3,        // [4][8192][10]
  OFF_NX1  = OFF_FEAF + 4*8192*10,       // [4][4096][3]
  OFF_L1F  = OFF_NX1  + 4*4096*3,        // [4][4096][32]
  OFF_NX2  = OFF_L1F  + 4*4096*32,       // [4][1024][3]
  OFF_L2F  = OFF_NX2  + 4*1024*3,        // [4][1024][64]
  OFF_UH2  = OFF_L2F  + 4*1024*64,       // [4][4096][32]
  OFF_L1N  = OFF_UH2  + 4*4096*32,       // [4][4096][32]
  OFF_H3   = OFF_L1N  + 4*4096*32,       // [4][8192][32]
  OFF_L0N  = OFF_H3   + 4*8192*32,       // [4][8192][32]
  OFF_STATS= OFF_L0N  + 4*8192*32,       // 2048 f32 (2 pipes x 1024)
  OFF_GIDX1= OFF_STATS + 2048,           // [4][4096][16] int
  OFF_GIDX2= OFF_GIDX1 + 4*4096*16,      // [4][1024][16]
  OFF_UIDX = OFF_GIDX2 + 4*1024*16,      // [4][4096][8]
  WS_END   = OFF_UIDX + 4*4096*8
};
enum : int { ST_SA1A=0, ST_SA1B=64, ST_SA2A=128, ST_SA2B=192, ST_U1=320, ST_U2=384, ST_FP=448, ST_BN1=512 };

// XLA-style contracted squared-norm and dot (fma chains, ascending c)
DI float nrm3(float x, float y, float z){ return fmaf(z,z, fmaf(y,y, x*x)); }
DI float dot3(float ax,float ay,float az,float bx,float by,float bz){
  return fmaf(az,bz, fmaf(ay,by, ax*bx));
}

// ---- f64-as-u64-key reduce-to-lane63, DPP only (VALU pipe, no LDS) ----
// Key = (f32 distBits << 32) | (N-1-origIdx), dist >= 0 finite. For such
// keys, u64 ordering == f64 numeric ordering (nonneg, exp!=0x7FF), so
// v_max_f64 implements lexicographic (dist desc, origIdx asc) selection.
// Harness-validated in R3.
template<int CTRL>
DI double kstage(double v){
  int lo = __builtin_amdgcn_update_dpp(0, __double2loint(v), CTRL, 0xf, 0xf, true);
  int hi = __builtin_amdgcn_update_dpp(0, __double2hiint(v), CTRL, 0xf, 0xf, true);
  return fmax(v, __hiloint2double(hi, lo));
}
DI double red63_kmax(double v){
  v = kstage<0x111>(v);  // row_shr:1
  v = kstage<0x112>(v);  // row_shr:2
  v = kstage<0x114>(v);  // row_shr:4
  v = kstage<0x118>(v);  // row_shr:8
  v = kstage<0x142>(v);  // row_bcast:15
  v = kstage<0x143>(v);  // row_bcast:31
  return v;              // lane 63 holds the wave max
}

// ---------------- block stats reduce: sum & sumsq per channel ----------------
template<int CH>
DI void stats_accum(float* h, float* dst, float (*sred)[128])
{
  float sq[CH];
  #pragma unroll
  for (int c=0;c<CH;c++) sq[c]=h[c]*h[c];
  #pragma unroll
  for (int m=1;m<64;m<<=1){
    #pragma unroll
    for (int c=0;c<CH;c++){ h[c] += __shfl_xor(h[c], m, 64); sq[c] += __shfl_xor(sq[c], m, 64); }
  }
  const int tid=threadIdx.x, wid=tid>>6, lane=tid&63;
  if (lane==0){
    #pragma unroll
    for (int c=0;c<CH;c++){ sred[wid][c]=h[c]; sred[wid][CH+c]=sq[c]; }
  }
  __syncthreads();
  if (tid < 2*CH){
    float v = sred[0][tid]+sred[1][tid]+sred[2][tid]+sred[3][tid];
    atomicAdd(dst+tid, v);
  }
}

// ---------------- prep: gather both pipes into one z-indexed layout ----------------
__global__ __launch_bounds__(256) void prep(const float* __restrict__ p1,const float* __restrict__ f1,
                                            const float* __restrict__ p2,const float* __restrict__ f2,
                                            float* __restrict__ xyzf, float* __restrict__ feaf)
{
  const int i = blockIdx.x*256+threadIdx.x;          // 0..32767 = (z,n)
  const int z = i>>13, n = i&8191, pipe=z>>1, b=z&1;
  const float* ps = (pipe?p2:p1) + (b*8192+n)*3;
  const float* fs = (pipe?f2:f1) + (b*8192+n)*10;
  float* xo = xyzf + (z*8192+n)*3;
  float* fo = feaf + (z*8192+n)*10;
  #pragma unroll
  for (int c=0;c<3;c++)  xo[c]=ps[c];
  #pragma unroll
  for (int c=0;c<10;c++) fo[c]=fs[c];
}

// ---------------- farthest point sampling: ONE WAVE, barrier-free loop ----------------
// 64 threads/block, one block per batch z, wave-synchronous throughout.
// Per-point state lives in LDS (NOT registers -- R4's register dist[] spilled
// to scratch and was 10x slower):
//   pts4[N] = float4(x,y,z,DIST), lane-interleaved [k*64+lane] so the rescan's
//             ds_read_b128 (stride 16B across lanes) is conflict-free and
//             fetches coords+dist in ONE op. Dist write-back (b32 at +12) is
//             predicated on actual shrink.
//   oi16[N] = original index (u16, stride-2 reads = free 2-way aliasing).
// Per-sub cached state (NSUB=P/16 subs of 16 pts) stays in registers:
//   bbox (6), submax lm, min-orig-idx jb, best coords (3) -> 11*NSUB VGPRs.
// Main loop (NO barriers, NO global reads):
//   1. wave winner via f64-key DPP reduce + readlane(63).
//   2. owner = ffs(ballot(mykey==skey)); coords via readlane(.,owner).
//   3. lane 0 streams winner coords to nx (fire-and-forget store).
//   4. lane bbox prune, then per-sub prune: skip sub if lb*0.99999 >= lm_s
//      (bit-exact: reference's fminf provably a no-op then; ~9ulp bound
//      << 1e-5 slack; harness-validated R1/R2/R3).
//   5. rescan hit subs from LDS, identical fmaf/fminf chain as reference.
// Init dist=1e10 -> step-0 winner is orig index 0 (ref far=0). Selection ==
// reference first-occurrence argmax (dist desc, orig idx asc).
DI int mspread(int v){ return (v&1) | ((v&2)<<2) | ((v&4)<<4); }   // 3b -> bits 0,3,6

template<int N,int NPOINT>
__global__ __launch_bounds__(64,1) void fps_solo(const float* __restrict__ src, float* __restrict__ dst)
{
  constexpr int P = N/64, NSUB = P/16;
  const int z = blockIdx.x;
  const float* xyz = src + z*N*3;
  float* nx = dst + z*NPOINT*3;
  const int lane = threadIdx.x;

  __shared__ float4 pts4[N];              // [k*64+lane], w = running dist
  __shared__ unsigned short oi16[N];      // [k*64+lane], orig idx
  __shared__ int hist[512], offs[512];

  // ---- pass A: histogram of 8^3 morton cells ----
  for (int i=lane;i<512;i+=64) hist[i]=0;
  __syncthreads();
  for (int i=0;i<P;i++){
    const int j = lane + i*64;
    float x=xyz[j*3], y=xyz[j*3+1], zz=xyz[j*3+2];
    int a=(int)(x*8.f);  a=a<0?0:(a>7?7:a);
    int b=(int)(y*8.f);  b=b<0?0:(b>7?7:b);
    int c=(int)(zz*8.f); c=c<0?0:(c>7?7:c);
    int mc = mspread(a) | (mspread(b)<<1) | (mspread(c)<<2);
    atomicAdd(&hist[mc],1);
  }
  __syncthreads();
  // ---- pass B: exclusive prefix over 512 cells (single-wave scan) ----
  {
    int loc[8]; int ssum=0;
    #pragma unroll
    for (int i=0;i<8;i++){ loc[i]=hist[lane*8+i]; ssum+=loc[i]; }
    int ix=ssum;
    #pragma unroll
    for (int m=1;m<64;m<<=1){ int y=__shfl_up(ix,m,64); if (lane>=m) ix+=y; }
    int base = ix - ssum;
    #pragma unroll
    for (int i=0;i<8;i++){ offs[lane*8+i]=base; base+=loc[i]; }
  }
  __syncthreads();
  // ---- pass C: scatter into lane-interleaved layout (intra-cell order
  //      nondeterministic; result exact: keys tie-break on orig idx, prune
  //      is order-free, per-point distances are exact) ----
  for (int i=0;i<P;i++){
    const int j = lane + i*64;
    float x=xyz[j*3], y=xyz[j*3+1], zz=xyz[j*3+2];
    int a=(int)(x*8.f);  a=a<0?0:(a>7?7:a);
    int b=(int)(y*8.f);  b=b<0?0:(b>7?7:b);
    int c=(int)(zz*8.f); c=c<0?0:(c>7?7:c);
    int mc = mspread(a) | (mspread(b)<<1) | (mspread(c)<<2);
    int pos = atomicAdd(&offs[mc],1);
    int slot = (pos%P)*64 + (pos/P);
    pts4[slot] = make_float4(x,y,zz,1e10f);
    oi16[slot] = (unsigned short)j;
  }
  __syncthreads();
  // ---- pass D: per-sub cached state from LDS ----
  float sb_lox[NSUB],sb_hix[NSUB],sb_loy[NSUB],sb_hiy[NSUB],sb_loz[NSUB],sb_hiz[NSUB];
  float sb_lm[NSUB], sb_bx[NSUB], sb_by[NSUB], sb_bz[NSUB];
  int   sb_jb[NSUB];
  #pragma unroll
  for (int sub=0; sub<NSUB; sub++){
    float lox=1e30f,hix=-1e30f,loy=1e30f,hiy=-1e30f,loz=1e30f,hiz=-1e30f;
    int jmin=0x7fffffff; float jx=0.f,jy=0.f,jz=0.f;
    for (int kk=0; kk<16; kk++){
      int slot = (sub*16+kk)*64 + lane;
      float4 p = pts4[slot];
      int oi = oi16[slot];
      lox=fminf(lox,p.x); hix=fmaxf(hix,p.x);
      loy=fminf(loy,p.y); hiy=fmaxf(hiy,p.y);
      loz=fminf(loz,p.z); hiz=fmaxf(hiz,p.z);
      bool c = oi<jmin;
      jmin = c?oi:jmin; jx = c?p.x:jx; jy = c?p.y:jy; jz = c?p.z:jz;
    }
    sb_lox[sub]=lox; sb_hix[sub]=hix; sb_loy[sub]=loy; sb_hiy[sub]=hiy;
    sb_loz[sub]=loz; sb_hiz[sub]=hiz;
    sb_lm[sub]=1e10f; sb_jb[sub]=jmin; sb_bx[sub]=jx; sb_by[sub]=jy; sb_bz[sub]=jz;
  }
  // lane-level bbox (union)
  float blox=sb_lox[0],bhix=sb_hix[0],bloy=sb_loy[0],bhiy=sb_hiy[0],bloz=sb_loz[0],bhiz=sb_hiz[0];
  #pragma unroll
  for (int sub=1; sub<NSUB; sub++){
    blox=fminf(blox,sb_lox[sub]); bhix=fmaxf(bhix,sb_hix[sub]);
    bloy=fminf(bloy,sb_loy[sub]); bhiy=fmaxf(bhiy,sb_hiy[sub]);
    bloz=fminf(bloz,sb_loz[sub]); bhiz=fmaxf(bhiz,sb_hiz[sub]);
  }
  float lmv, bxv, byv, bzv; int jbv; double mykey;
  auto rebuild = [&](){
    float L=sb_lm[0]; int J=sb_jb[0]; float X=sb_bx[0],Y=sb_by[0],Z=sb_bz[0];
    #pragma unroll
    for (int sub=1; sub<NSUB; sub++){
      bool c = (sb_lm[sub]>L) || (sb_lm[sub]==L && sb_jb[sub]<J);
      L=c?sb_lm[sub]:L; J=c?sb_jb[sub]:J;
      X=c?sb_bx[sub]:X; Y=c?sb_by[sub]:Y; Z=c?sb_bz[sub]:Z;
    }
    lmv=L; jbv=J; bxv=X; byv=Y; bzv=Z;
    mykey = __hiloint2double(__float_as_int(L), N-1-J);
  };
  rebuild();

  // ---- main serial loop: wave-synchronous, zero barriers, zero global reads ----
  for (int s=0;;s++){
    // 1. wave winner key
    double wk = red63_kmax(mykey);
    int glo = __builtin_amdgcn_readlane(__double2loint(wk), 63);
    int ghi = __builtin_amdgcn_readlane(__double2hiint(wk), 63);
    double skey = __hiloint2double(ghi, glo);
    // 2. owner lane -> winner coords via uniform readlane
    unsigned long long bal = __ballot(mykey == skey);
    int owner = __ffsll((unsigned long long)bal) - 1;
    float cx = __int_as_float(__builtin_amdgcn_readlane(__float_as_int(bxv), owner));
    float cy = __int_as_float(__builtin_amdgcn_readlane(__float_as_int(byv), owner));
    float cz = __int_as_float(__builtin_amdgcn_readlane(__float_as_int(bzv), owner));
    // 3. stream winner coords (nothing ever waits on these stores)
    if (lane==0){ nx[s*3]=cx; nx[s*3+1]=cy; nx[s*3+2]=cz; }
    if (s==NPOINT-1) break;
    // 4. lane-level prune
    float dxm = fmaxf(fmaxf(blox-cx, cx-bhix), 0.f);
    float dym = fmaxf(fmaxf(bloy-cy, cy-bhiy), 0.f);
    float dzm = fmaxf(fmaxf(bloz-cz, cz-bhiz), 0.f);
    float lb  = fmaf(dzm,dzm, fmaf(dym,dym, dxm*dxm));
    if (lb*0.99999f < lmv){
      bool changed = false;
      #pragma unroll
      for (int sub=0; sub<NSUB; sub++){
        float sxm = fmaxf(fmaxf(sb_lox[sub]-cx, cx-sb_hix[sub]), 0.f);
        float sym = fmaxf(fmaxf(sb_loy[sub]-cy, cy-sb_hiy[sub]), 0.f);
        float szm = fmaxf(fmaxf(sb_loz[sub]-cz, cz-sb_hiz[sub]), 0.f);
        float lbs = fmaf(szm,szm, fmaf(sym,sym, sxm*sxm));
        if (lbs*0.99999f < sb_lm[sub]){
          float nm=-1.f; int nj=0x7fffffff; float nbx=0.f,nby=0.f,nbz=0.f;
          for (int kk=0; kk<16; kk++){
            int slot = (sub*16+kk)*64 + lane;
            float4 p = pts4[slot];
            int oi = oi16[slot];
            float dx=p.x-cx, dy=p.y-cy, dz=p.z-cz;
            float d  = fmaf(dz,dz, fmaf(dy,dy, dx*dx));   // XLA fma chain
            float nd = fminf(p.w, d);
            if (nd < p.w) pts4[slot].w = nd;              // predicated write-back
            bool c = (nd>nm) || (nd==nm && oi<nj);
            nm=c?nd:nm; nj=c?oi:nj; nbx=c?p.x:nbx; nby=c?p.y:nby; nbz=c?p.z:nbz;
          }
          sb_lm[sub]=nm; sb_jb[sub]=nj; sb_bx[sub]=nbx; sb_by[sub]=nby; sb_bz[sub]=nbz;
          changed = true;
        }
      }
      if (changed) rebuild();
    }
  }
}

// ---------------- ball query: first K in-radius indices (ascending) + argmin fallback ----
template<int NSRC,int SQ,int K>
__global__ __launch_bounds__(64) void ball_query(const float* __restrict__ qxyz, const float* __restrict__ sxyz,
                                                 int* __restrict__ gidx, float r2)
{
  __shared__ float4 tile[1024];
  const int z = blockIdx.y, tid = threadIdx.x;
  const int s = blockIdx.x*64 + tid;
  const float* q = qxyz + (z*SQ+s)*3;
  const float qx=q[0],qy=q[1],qz=q[2];
  const float qq=nrm3(qx,qy,qz);
  int cnt=0, first=0, amin=0; float dmin=3.0e38f;
  int* out = gidx + (z*SQ+s)*K;
  for (int t0=0;t0<NSRC;t0+=1024){
    __syncthreads();
    for (int i=tid;i<1024;i+=64){
      const float* p = sxyz + (z*NSRC+t0+i)*3;
      float x=p[0],y=p[1],w=p[2];
      tile[i]=make_float4(x,y,w,nrm3(x,y,w));
    }
    __syncthreads();
    for (int jj=0;jj<1024;jj++){
      float4 p = tile[jj];
      float dot=dot3(qx,qy,qz,p.x,p.y,p.z);
      float d=(qq+p.w)-2.0f*dot;
      const int j = t0+jj;
      if (d < dmin){ dmin=d; amin=j; }
      if (d <= r2 && cnt < K){ if(cnt==0) first=j; out[cnt]=j; cnt++; }
    }
  }
  const int fill = (cnt==0)? amin : first;
  for (int c=cnt;c<K;c++) out[c]=fill;
}

// ---------------- set-abstraction conv passes ----------------
template<int S,int K,int CF,int C1,int C2,int NSRC,int PASS>
__global__ __launch_bounds__(256) void sa_pass(
    const float* __restrict__ srcxyz, const float* __restrict__ srcfea,
    const float* __restrict__ qxyz, const int* __restrict__ gidx,
    const float* __restrict__ w0, const float* __restrict__ g0, const float* __restrict__ b0,
    const float* __restrict__ w1, const float* __restrict__ g1v, const float* __restrict__ b1v,
    float* __restrict__ stats, int offA, int offB, float cnt0, float cnt1,
    float* __restrict__ outp)
{
  constexpr int CIN = 3+CF;
  __shared__ float w0l[C1*CIN];
  __shared__ float w1l[PASS>=2 ? C2*C1 : 1];
  __shared__ float sc0[C1], bi0[C1];
  __shared__ float sc1[C2], bi1[C2];
  __shared__ float sred[4][128];
  const int z = blockIdx.y, pipe = z>>1, tid = threadIdx.x;
  float* stA = stats + pipe*1024 + offA;
  float* stB = stats + pipe*1024 + offB;
  for (int i=tid;i<C1*CIN;i+=256) w0l[i]=w0[i];
  if (PASS>=2){
    for (int i=tid;i<C2*C1;i+=256) w1l[i]=w1[i];
    if (tid<C1){
      float m = stA[tid]/cnt0;
      float var = stA[C1+tid]/cnt0 - m*m;
      float rs = 1.0f/sqrtf(var+1e-5f);
      float sc = rs*g0[tid];
      sc0[tid]=sc; bi0[tid]=b0[tid]-m*sc;
    }
  }
  if (PASS==3 && tid<C2){
    float m = stB[tid]/cnt1;
    float var = stB[C2+tid]/cnt1 - m*m;
    float rs = 1.0f/sqrtf(var+1e-5f);
    float sc = rs*g1v[tid];
    sc1[tid]=sc; bi1[tid]=b1v[tid]-m*sc;
  }
  __syncthreads();
  const int item = blockIdx.x*256+tid;
  const int s = item/K;
  const int j = gidx[(z*S+s)*K + (item%K)];
  const float* q = qxyz + (z*S+s)*3;
  const float* p = srcxyz + (z*NSRC+j)*3;
  float f[CIN];
  f[0]=p[0]-q[0]; f[1]=p[1]-q[1]; f[2]=p[2]-q[2];
  const float* fe = srcfea + (z*NSRC+j)*CF;
  #pragma unroll
  for (int c=0;c<CF;c++) f[3+c]=fe[c];
  float h1[C1];
  #pragma unroll
  for (int o=0;o<C1;o++){
    float a=0.f;
    #pragma unroll
    for (int c=0;c<CIN;c++) a = fmaf(w0l[o*CIN+c], f[c], a);
    h1[o]=a;
  }
  if (PASS==1){ stats_accum<C1>(h1, stA, sred); return; }
  float f2v[C1];
  #pragma unroll
  for (int o=0;o<C1;o++) f2v[o]=fmaxf(fmaf(h1[o],sc0[o],bi0[o]), 0.f);
  float h2[C2];
  #pragma unroll
  for (int o=0;o<C2;o++){
    float a=0.f;
    #pragma unroll
    for (int c=0;c<C1;c++) a = fmaf(w1l[o*C1+c], f2v[c], a);
    h2[o]=a;
  }
  if (PASS==2){ stats_accum<C2>(h2, stB, sred); return; }
  #pragma unroll
  for (int o=0;o<C2;o++) h2[o]=fmaxf(fmaf(h2[o],sc1[o],bi1[o]), 0.f);
  #pragma unroll
  for (int msk=1; msk<K; msk<<=1){
    #pragma unroll
    for (int o=0;o<C2;o++) h2[o]=fmaxf(h2[o], __shfl_xor(h2[o], msk, 64));
  }
  if ((tid & (K-1))==0){
    float* op = outp + (z*S+s)*C2;
    #pragma unroll
    for (int o=0;o<C2;o++) op[o]=h2[o];
  }
}

// ---------------- upconv: stable 8-NN (64-thread blocks, order-preserving) ----------------
__global__ __launch_bounds__(64) void up_top8(const float* __restrict__ nx1, const float* __restrict__ nx2,
                                              int* __restrict__ uidx)
{
  __shared__ float4 tile[1024];
  const int z=blockIdx.y, tid=threadIdx.x;
  const int s=blockIdx.x*64+tid;
  const float* q = nx1 + (z*4096+s)*3;
  const float qx=q[0],qy=q[1],qz=q[2];
  const float qq=nrm3(qx,qy,qz);
  for (int i=tid;i<1024;i+=64){
    const float* p = nx2 + (z*1024+i)*3;
    float x=p[0],y=p[1],w=p[2];
    tile[i]=make_float4(x,y,w,nrm3(x,y,w));
  }
  __syncthreads();
  float d[8]; int id[8];
  #pragma unroll
  for (int r=0;r<8;r++){ d[r]=3e38f; id[r]=0; }
  for (int j=0;j<1024;j++){
    float4 p=tile[j];
    float dt=dot3(qx,qy,qz,p.x,p.y,p.z);
    float dd=(qq+p.w)-2.0f*dt;
    if (dd<d[7]){
      d[7]=dd; id[7]=j;
      #pragma unroll
      for (int r=7;r>0;r--){
        if (d[r]<d[r-1]){ float td=d[r-1]; d[r-1]=d[r]; d[r]=td; int ti=id[r-1]; id[r-1]=id[r]; id[r]=ti; }
      }
    }
  }
  int* o = uidx + (z*4096+s)*8;
  #pragma unroll
  for (int r=0;r<8;r++) o[r]=id[r];
}

template<int PASS>
__global__ __launch_bounds__(256) void up_pass(
    const float* __restrict__ nx1, const float* __restrict__ nx2,
    const float* __restrict__ l2f, const float* __restrict__ l1f,
    const int* __restrict__ uidx,
    const float* __restrict__ w1, const float* __restrict__ g1v, const float* __restrict__ b1v,
    const float* __restrict__ w2,
    float* __restrict__ stats, float* __restrict__ uh2)
{
  __shared__ float w1l[32*67];
  __shared__ float w2l[PASS==2?32*64:1];
  __shared__ float sc0[32], bi0[32];
  __shared__ float sred[4][128];
  const int z=blockIdx.y, pipe=z>>1, tid=threadIdx.x;
  float* stU1 = stats + pipe*1024 + ST_U1;
  float* stU2 = stats + pipe*1024 + ST_U2;
  for (int i=tid;i<32*67;i+=256) w1l[i]=w1[i];
  if (PASS==2){
    for (int i=tid;i<32*64;i+=256) w2l[i]=w2[i];
    if (tid<32){
      float m=stU1[tid]/65536.f;
      float var=stU1[32+tid]/65536.f - m*m;
      float rs=1.0f/sqrtf(var+1e-5f);
      float sc=rs*g1v[tid];
      sc0[tid]=sc; bi0[tid]=b1v[tid]-m*sc;
    }
  }
  __syncthreads();
  const int item = blockIdx.x*256+tid;
  const int s = item>>3, k = item&7;
  const int j = uidx[(z*4096+s)*8+k];
  float f67[67];
  const float* fe = l2f + (z*1024+j)*64;
  #pragma unroll
  for (int c=0;c<64;c++) f67[c]=fe[c];
  const float* pp = nx2 + (z*1024+j)*3;
  const float* qv = nx1 + (z*4096+s)*3;
  f67[64]=pp[0]-qv[0]; f67[65]=pp[1]-qv[1]; f67[66]=pp[2]-qv[2];
  float h[32];
  #pragma unroll
  for (int o=0;o<32;o++){
    float a=0.f;
    #pragma unroll
    for (int c=0;c<67;c++) a=fmaf(w1l[o*67+c], f67[c], a);
    h[o]=a;
  }
  if (PASS==1){ stats_accum<32>(h, stU1, sred); return; }
  #pragma unroll
  for (int o=0;o<32;o++) h[o]=fmaxf(fmaf(h[o],sc0[o],bi0[o]),0.f);
  #pragma unroll
  for (int msk=1; msk<8; msk<<=1){
    #pragma unroll
    for (int o=0;o<32;o++) h[o]=fmaxf(h[o], __shfl_xor(h[o],msk,64));
  }
  float h2[32];
  if (k==0){
    const float* l1 = l1f + (z*4096+s)*32;
    #pragma unroll
    for (int o=0;o<32;o++){
      float a=0.f;
      #pragma unroll
      for (int c=0;c<32;c++) a=fmaf(w2l[o*64+c], h[c], a);
      #pragma unroll
      for (int c=0;c<32;c++) a=fmaf(w2l[o*64+32+c], l1[c], a);
      h2[o]=a;
    }
    float* up = uh2 + (z*4096+s)*32;
    #pragma unroll
    for (int o=0;o<32;o++) up[o]=h2[o];
  } else {
    #pragma unroll
    for (int o=0;o<32;o++) h2[o]=0.f;
  }
  stats_accum<32>(h2, stU2, sred);
}

__global__ __launch_bounds__(256) void up_norm(const float* __restrict__ uh2, const float* __restrict__ g,
                                               const float* __restrict__ b, const float* __restrict__ stats,
                                               float* __restrict__ l1n)
{
  const int i = blockIdx.x*256+threadIdx.x;   // < 4*4096*32
  const int z = i>>17, pipe = z>>1, c = i&31;
  const float* st = stats + pipe*1024 + ST_U2;
  float m = st[c]/8192.f;
  float var = st[32+c]/8192.f - m*m;
  float rs = 1.0f/sqrtf(var+1e-5f);
  float sc = rs*g[c];
  float bi = b[c]-m*sc;
  l1n[i]=fmaxf(fmaf(uh2[i],sc,bi),0.f);
}

// ---------------- feature propagation: 3-NN interpolate + conv ----------------
__global__ __launch_bounds__(256) void fp_kern(
  const float* __restrict__ xyzf, const float* __restrict__ feaf,
  const float* __restrict__ nx1, const float* __restrict__ l1n,
  const float* __restrict__ fpw, float* __restrict__ stats, float* __restrict__ h3)
{
  __shared__ float4 tile[2048];
  __shared__ float wl[32*42];
  __shared__ float sred[4][128];
  const int z=blockIdx.y, pipe=z>>1, tid=threadIdx.x;
  for (int i=tid;i<32*42;i+=256) wl[i]=fpw[i];
  const int n = blockIdx.x*256+tid;
  const float* q = xyzf + (z*8192+n)*3;
  const float qx=q[0],qy=q[1],qz=q[2];
  const float qq2=nrm3(qx,qy,qz);
  float d0=3e38f,d1=3e38f,d2=3e38f; int i0=0,i1=0,i2=0;
  for (int t0=0;t0<4096;t0+=2048){
    __syncthreads();
    for (int i=tid;i<2048;i+=256){
      const float* p = nx1 + (z*4096+t0+i)*3;
      float x=p[0],y=p[1],w=p[2];
      tile[i]=make_float4(x,y,w,nrm3(x,y,w));
    }
    __syncthreads();
    for (int jj=0;jj<2048;jj++){
      float4 p=tile[jj];
      float dt=dot3(qx,qy,qz,p.x,p.y,p.z);
      float d=(qq2+p.w)-2.0f*dt;
      if (d<d2){
        d2=d; i2=t0+jj;
        if (d2<d1){ float td=d1; d1=d2; d2=td; int ti=i1; i1=i2; i2=ti; }
        if (d1<d0){ float td=d0; d0=d1; d1=td; int ti=i0; i0=i1; i1=ti; }
      }
    }
  }
  d0=fmaxf(d0,1e-10f); d1=fmaxf(d1,1e-10f); d2=fmaxf(d2,1e-10f);
  float w0=1.0f/d0, w1=1.0f/d1, w2=1.0f/d2;
  float wsum=(w0+w1)+w2;
  w0/=wsum; w1/=wsum; w2/=wsum;
  const float* A = l1n + (z*4096+i0)*32;
  const float* B = l1n + (z*4096+i1)*32;
  const float* C = l1n + (z*4096+i2)*32;
  float f[42];
  #pragma unroll
  for (int c=0;c<32;c++) f[c]=fmaf(C[c],w2, fmaf(B[c],w1, A[c]*w0));
  const float* fe = feaf + (z*8192+n)*10;
  #pragma unroll
  for (int c=0;c<10;c++) f[32+c]=fe[c];
  float h[32];
  #pragma unroll
  for (int o=0;o<32;o++){
    float a=0.f;
    #pragma unroll
    for (int c=0;c<42;c++) a=fmaf(wl[o*42+c], f[c], a);
    h[o]=a;
    h3[(z*8192+n)*32+o]=a;
  }
  stats_accum<32>(h, stats + pipe*1024 + ST_FP, sred);
}

__global__ __launch_bounds__(256) void fp_post(const float* __restrict__ h3, const float* __restrict__ g,
                                               const float* __restrict__ b, float* __restrict__ stats,
                                               float* __restrict__ l0n)
{
  __shared__ float sc[32], bi[32];
  __shared__ float sred[4][128];
  const int tid=threadIdx.x;
  const int row = blockIdx.x*256+tid;     // 32768
  const int pipe = row>>14;
  float* stF = stats + pipe*1024 + ST_FP;
  float* stB = stats + pipe*1024 + ST_BN1;
  if (tid<32){
    float m=stF[tid]/16384.f;
    float var=stF[32+tid]/16384.f-m*m;
    float rs=1.0f/sqrtf(var+1e-5f);
    float s=rs*g[tid];
    sc[tid]=s; bi[tid]=b[tid]-m*s;
  }
  __syncthreads();
  float x[32];
  #pragma unroll
  for (int c=0;c<32;c++){ x[c]=fmaxf(fmaf(h3[row*32+c],sc[c],bi[c]),0.f); l0n[row*32+c]=x[c]; }
  stats_accum<32>(x, stB, sred);
}

__global__ __launch_bounds__(256) void final_kern(
  const float* __restrict__ l0n, const float* __restrict__ g, const float* __restrict__ b,
  const float* __restrict__ cw, const float* __restrict__ cb,
  const float* __restrict__ p1, const float* __restrict__ p2,
  const float* __restrict__ stats, float* __restrict__ out)
{
  __shared__ float sc[32], bi[32], wl[512], bl[16];
  const int tid=threadIdx.x;
  const int row = blockIdx.x*256+tid;
  const int z=row>>13, pipe=z>>1, bb=z&1, n=row&8191;
  const float* st = stats + pipe*1024 + ST_BN1;
  if (tid<32){
    float m=st[tid]/16384.f;
    float var=st[32+tid]/16384.f-m*m;
    float rs=1.0f/sqrtf(var+1e-5f);
    float s=rs*g[tid];
    sc[tid]=s; bi[tid]=b[tid]-m*s;
  }
  for (int i=tid;i<512;i+=256) wl[i]=cw[i];
  if (tid<16) bl[tid]=cb[tid];
  __syncthreads();
  float x[32];
  #pragma unroll
  for (int c=0;c<32;c++) x[c]=fmaxf(fmaf(l0n[row*32+c],sc[c],bi[c]),0.f);
  float* o = out + row*19;
  const float* ps = (pipe?p2:p1) + (bb*8192+n)*3;
  o[0]=ps[0]; o[1]=ps[1]; o[2]=ps[2];
  #pragma unroll
  for (int oo=0;oo<16;oo++){
    float a=0.f;
    #pragma unroll
    for (int c=0;c<32;c++) a=fmaf(wl[oo*32+c],x[c],a);
    o[3+oo]=a+bl[oo];
  }
}

// ---------------- host ----------------
extern "C" void kernel_launch(void* const* d_in, const int* in_sizes, int n_in,
                              void* d_out, int out_size, void* d_ws, size_t ws_size,
                              hipStream_t stream)
{
  (void)in_sizes; (void)n_in; (void)out_size; (void)ws_size;
  const float* p1 = (const float*)d_in[0];
  const float* f1 = (const float*)d_in[1];
  const float* p2 = (const float*)d_in[2];
  const float* f2 = (const float*)d_in[3];
  const float *sa1_w0=(const float*)d_in[4], *sa1_g0=(const float*)d_in[5], *sa1_b0=(const float*)d_in[6];
  const float *sa1_w1=(const float*)d_in[7], *sa1_g1=(const float*)d_in[8], *sa1_b1=(const float*)d_in[9];
  const float *sa2_w0=(const float*)d_in[10],*sa2_g0=(const float*)d_in[11],*sa2_b0=(const float*)d_in[12];
  const float *sa2_w1=(const float*)d_in[13],*sa2_g1=(const float*)d_in[14],*sa2_b1=(const float*)d_in[15];
  const float *su1_w1=(const float*)d_in[16],*su1_g1=(const float*)d_in[17],*su1_b1=(const float*)d_in[18];
  const float *su1_w2=(const float*)d_in[19],*su1_g2=(const float*)d_in[20],*su1_b2=(const float*)d_in[21];
  const float *fp_w=(const float*)d_in[22], *fp_g=(const float*)d_in[23], *fp_b=(const float*)d_in[24];
  const float *bn1_g=(const float*)d_in[25],*bn1_b=(const float*)d_in[26];
  const float *conv2_w=(const float*)d_in[27],*conv2_b=(const float*)d_in[28];
  float* wsf=(float*)d_ws; int* wsi=(int*)d_ws;
  float* xyzf=wsf+OFF_XYZF; float* feaf=wsf+OFF_FEAF;
  float* nx1=wsf+OFF_NX1; float* l1f=wsf+OFF_L1F;
  float* nx2=wsf+OFF_NX2; float* l2f=wsf+OFF_L2F;
  float* uh2=wsf+OFF_UH2; float* l1n=wsf+OFF_L1N;
  float* h3=wsf+OFF_H3; float* l0n=wsf+OFF_L0N;
  float* stats=wsf+OFF_STATS;
  int* gidx1=wsi+OFF_GIDX1; int* gidx2=wsi+OFF_GIDX2; int* uidx=wsi+OFF_UIDX;
  // radius*radius is computed in Python f64 then demoted to f32
  const float R2A=(float)(0.1*0.1), R2B=(float)(0.2*0.2);

  (void)hipMemsetAsync(stats, 0, 2048*sizeof(float), stream);
  prep<<<128,256,0,stream>>>(p1,f1,p2,f2,xyzf,feaf);
  fps_solo<8192,4096><<<4,64,0,stream>>>(xyzf, nx1);
  ball_query<8192,4096,16><<<dim3(64,4),64,0,stream>>>(nx1, xyzf, gidx1, R2A);
  sa_pass<4096,16,10,16,32,8192,1><<<dim3(256,4),256,0,stream>>>(xyzf,feaf,nx1,gidx1,
      sa1_w0,sa1_g0,sa1_b0,sa1_w1,sa1_g1,sa1_b1, stats,ST_SA1A,ST_SA1B,131072.f,131072.f, l1f);
  sa_pass<4096,16,10,16,32,8192,2><<<dim3(256,4),256,0,stream>>>(xyzf,feaf,nx1,gidx1,
      sa1_w0,sa1_g0,sa1_b0,sa1_w1,sa1_g1,sa1_b1, stats,ST_SA1A,ST_SA1B,131072.f,131072.f, l1f);
  sa_pass<4096,16,10,16,32,8192,3><<<dim3(256,4),256,0,stream>>>(xyzf,feaf,nx1,gidx1,
      sa1_w0,sa1_g0,sa1_b0,sa1_w1,sa1_g1,sa1_b1, stats,ST_SA1A,ST_SA1B,131072.f,131072.f, l1f);
  fps_solo<4096,1024><<<4,64,0,stream>>>(nx1, nx2);
  ball_query<4096,1024,16><<<dim3(16,4),64,0,stream>>>(nx2, nx1, gidx2, R2B);
  sa_pass<1024,16,32,32,64,4096,1><<<dim3(64,4),256,0,stream>>>(nx1,l1f,nx2,gidx2,
      sa2_w0,sa2_g0,sa2_b0,sa2_w1,sa2_g1,sa2_b1, stats,ST_SA2A,ST_SA2B,32768.f,32768.f, l2f);
  sa_pass<1024,16,32,32,64,4096,2><<<dim3(64,4),256,0,stream>>>(nx1,l1f,nx2,gidx2,
      sa2_w0,sa2_g0,sa2_b0,sa2_w1,sa2_g1,sa2_b1, stats,ST_SA2A,ST_SA2B,32768.f,32768.f, l2f);
  sa_pass<1024,16,32,32,64,4096,3><<<dim3(64,4),256,0,stream>>>(nx1,l1f,nx2,gidx2,
      sa2_w0,sa2_g0,sa2_b0,sa2_w1,sa2_g1,sa2_b1, stats,ST_SA2A,ST_SA2B,32768.f,32768.f, l2f);
  up_top8<<<dim3(64,4),64,0,stream>>>(nx1,nx2,uidx);
  up_pass<1><<<dim3(128,4),256,0,stream>>>(nx1,nx2,l2f,l1f,uidx,su1_w1,su1_g1,su1_b1,su1_w2,stats,uh2);
  up_pass<2><<<dim3(128,4),256,0,stream>>>(nx1,nx2,l2f,l1f,uidx,su1_w1,su1_g1,su1_b1,su1_w2,stats,uh2);
  up_norm<<<2048,256,0,stream>>>(uh2,su1_g2,su1_b2,stats,l1n);
  fp_kern<<<dim3(32,4),256,0,stream>>>(xyzf,feaf,nx1,l1n,fp_w,stats,h3);
  fp_post<<<128,256,0,stream>>>(h3,fp_g,fp_b,stats,l0n);
  final_kern<<<128,256,0,stream>>>(l0n,bn1_g,bn1_b,conv2_w,conv2_b,p1,p2,stats,(float*)d_out);
}

// Round 6
// 5479.381 us; speedup vs baseline: 11.4548x; 11.4548x over previous
//
#include <hip/hip_runtime.h>

#define DI __device__ __forceinline__

// ---------------- workspace layout (4-byte element offsets) ----------------
enum : int {
  OFF_XYZF = 0,                          // [4][8192][3] f32 (z = pipe*2+b)
  OFF_FEAF = OFF_XYZF + 4*8192*3,        // [4][8192][10]
  OFF_NX1  = OFF_FEAF + 4*8192*10,       // [4][4096][3]
  OFF_L1F  = OFF_NX1  + 4*4096*3,        // [4][4096][32]
  OFF_NX2  = OFF_L1F  + 4*4096*32,       // [4][1024][3]
  OFF_L2F  = OFF_NX2  + 4*1024*3,        // [4][1024][64]
  OFF_UH2  = OFF_L2F  + 4*1024*64,       // [4][4096][32]
  OFF_L1N  = OFF_UH2  + 4*4096*32,       // [4][4096][32]
  OFF_H3   = OFF_L1N  + 4*4096*32,       // [4][8192][32]
  OFF_L0N  = OFF_H3   + 4*8192*32,       // [4][8192][32]
  OFF_STATS= OFF_L0N  + 4*8192*32,       // 2048 f32 (2 pipes x 1024)
  OFF_GIDX1= OFF_STATS + 2048,           // [4][4096][16] int
  OFF_GIDX2= OFF_GIDX1 + 4*4096*16,      // [4][1024][16]
  OFF_UIDX = OFF_GIDX2 + 4*1024*16,      // [4][4096][8]
  WS_END   = OFF_UIDX + 4*4096*8
};
enum : int { ST_SA1A=0, ST_SA1B=64, ST_SA2A=128, ST_SA2B=192, ST_U1=320, ST_U2=384, ST_FP=448, ST_BN1=512 };

// XLA-style contracted squared-norm and dot (fma chains, ascending c)
DI float nrm3(float x, float y, float z){ return fmaf(z,z, fmaf(y,y, x*x)); }
DI float dot3(float ax,float ay,float az,float bx,float by,float bz){
  return fmaf(az,bz, fmaf(ay,by, ax*bx));
}

// ---- f64-as-u64-key reduce-to-lane63, DPP only (VALU pipe, no LDS) ----
// Key = (f32 distBits << 32) | (N-1-origIdx), dist >= 0 finite. For such
// keys, u64 ordering == f64 numeric ordering (nonneg, exp!=0x7FF), so
// v_max_f64 implements lexicographic (dist desc, origIdx asc) selection.
// Harness-validated in R3. bound_ctrl=true fills 0 -> neutral for max.
template<int CTRL>
DI double kstage(double v){
  int lo = __builtin_amdgcn_update_dpp(0, __double2loint(v), CTRL, 0xf, 0xf, true);
  int hi = __builtin_amdgcn_update_dpp(0, __double2hiint(v), CTRL, 0xf, 0xf, true);
  return fmax(v, __hiloint2double(hi, lo));
}
DI double red63_kmax(double v){
  v = kstage<0x111>(v);  // row_shr:1
  v = kstage<0x112>(v);  // row_shr:2
  v = kstage<0x114>(v);  // row_shr:4
  v = kstage<0x118>(v);  // row_shr:8
  v = kstage<0x142>(v);  // row_bcast:15
  v = kstage<0x143>(v);  // row_bcast:31
  return v;              // lane 63 holds the wave max
}

// ---------------- block stats reduce: sum & sumsq per channel ----------------
template<int CH>
DI void stats_accum(float* h, float* dst, float (*sred)[128])
{
  float sq[CH];
  #pragma unroll
  for (int c=0;c<CH;c++) sq[c]=h[c]*h[c];
  #pragma unroll
  for (int m=1;m<64;m<<=1){
    #pragma unroll
    for (int c=0;c<CH;c++){ h[c] += __shfl_xor(h[c], m, 64); sq[c] += __shfl_xor(sq[c], m, 64); }
  }
  const int tid=threadIdx.x, wid=tid>>6, lane=tid&63;
  if (lane==0){
    #pragma unroll
    for (int c=0;c<CH;c++){ sred[wid][c]=h[c]; sred[wid][CH+c]=sq[c]; }
  }
  __syncthreads();
  if (tid < 2*CH){
    float v = sred[0][tid]+sred[1][tid]+sred[2][tid]+sred[3][tid];
    atomicAdd(dst+tid, v);
  }
}

// ---------------- prep: gather both pipes into one z-indexed layout ----------------
__global__ __launch_bounds__(256) void prep(const float* __restrict__ p1,const float* __restrict__ f1,
                                            const float* __restrict__ p2,const float* __restrict__ f2,
                                            float* __restrict__ xyzf, float* __restrict__ feaf)
{
  const int i = blockIdx.x*256+threadIdx.x;          // 0..32767 = (z,n)
  const int z = i>>13, n = i&8191, pipe=z>>1, b=z&1;
  const float* ps = (pipe?p2:p1) + (b*8192+n)*3;
  const float* fs = (pipe?f2:f1) + (b*8192+n)*10;
  float* xo = xyzf + (z*8192+n)*3;
  float* fo = feaf + (z*8192+n)*10;
  #pragma unroll
  for (int c=0;c<3;c++)  xo[c]=ps[c];
  #pragma unroll
  for (int c=0;c<10;c++) fo[c]=fs[c];
}

// ---------------- farthest point sampling (8-wave full scan, R0 structure) ----------------
// R0's measured-best scan (scalar f32 pair-unrolled + first-occurrence rescan)
// with two overheads removed:
//   - wave_fmax + wave_imin two-phase reduce (2x LDS-pipe swizzle/shfl) ->
//     ONE f64-key DPP reduce (R3-validated): key=(distbits<<32)|(N-1-j),
//     v_max_f64 == lexicographic (dist desc, j asc). Lane 63 holds the wave
//     winner and issues the single LDS atomicMax (u64 order == f64 order).
//   - per-step global nx store -> LDS ring swin[NPOINT], bulk write at end.
//     The per-step barrier then drains only lgkmcnt (cheap), not vmcnt.
// Winner sequence == global first-occurrence argmax (max dist, then min j);
// distance math bit-identical to XLA f32 fma chain (exact fminf/fmaxf).
template<int N,int NPOINT,int T>
__global__ __launch_bounds__(T) void fps_kernel(const float* __restrict__ src, float* __restrict__ dst)
{
  constexpr int P = N/T;
  const int z = blockIdx.x;
  const float* xyz = src + z*N*3;
  float* nx = dst + z*NPOINT*3;
  const int t = threadIdx.x;
  __shared__ float sx[N], sy[N], szz[N];
  __shared__ int swin[NPOINT];
  __shared__ unsigned long long s_acc[3];
  float px[P],py[P],pz[P],dist[P];
  #pragma unroll
  for (int k=0;k<P;k++){
    const int j = t + k*T;
    float x=xyz[j*3+0], y=xyz[j*3+1], w=xyz[j*3+2];
    px[k]=x; py[k]=y; pz[k]=w; dist[k]=1e10f;
    sx[j]=x; sy[j]=y; szz[j]=w;
  }
  if (t==0){ s_acc[0]=0ull; s_acc[1]=0ull; s_acc[2]=0ull; }
  __syncthreads();
  unsigned long long win = (unsigned long long)(unsigned)(N-1);  // index 0
  for (int s=0;;s++){
    const int cur = (N-1) - (int)(unsigned)(win & 0xffffffffull);
    if (t==0) swin[s] = cur;
    if (s == NPOINT-1) break;
    const float cx=sx[cur], cy=sy[cur], cz=szz[cur];   // LDS broadcast
    // ---- scan: f32 only, paired (R0/R9, measured best) ----
    float lm = -1.0f;
    #pragma unroll
    for (int k=0;k<P;k+=2){
      float dx0=px[k]-cx,   dy0=py[k]-cy,   dz0=pz[k]-cz;
      float dx1=px[k+1]-cx, dy1=py[k+1]-cy, dz1=pz[k+1]-cz;
      float d0 = fmaf(dz0,dz0, fmaf(dy0,dy0, dx0*dx0));   // XLA fma chain
      float d1 = fmaf(dz1,dz1, fmaf(dy1,dy1, dx1*dx1));
      float n0 = fminf(dist[k],   d0);
      float n1 = fminf(dist[k+1], d1);
      dist[k]=n0; dist[k+1]=n1;
      lm = fmaxf(lm, fmaxf(n0,n1));
    }
    // ---- local first-occurrence index (smallest k -> smallest j for this t) ----
    int kb = 0;
    #pragma unroll
    for (int k=P-1;k>=0;k--) if (dist[k]==lm) kb = k;
    // ---- single-phase wave reduce: f64-key DPP chain (no LDS-pipe ops) ----
    double mykey = __hiloint2double(__float_as_int(lm), N-1 - (t + kb*T));
    double wk = red63_kmax(mykey);
    // ---- cross-wave: lane 63 (reduce owner) does one packed LDS atomic ----
    if ((t&63)==63)
      atomicMax(&s_acc[s%3], (unsigned long long)__double_as_longlong(wk));
    if (t==0) s_acc[(s+1)%3] = 0ull;   // reset next buffer (2 barriers from its reads)
    __syncthreads();
    win = s_acc[s%3];                  // broadcast read
  }
  // ---- bulk winner write (no global stores inside the loop) ----
  __syncthreads();
  for (int i=t;i<NPOINT;i+=T){
    int j = swin[i];
    nx[i*3]=sx[j]; nx[i*3+1]=sy[j]; nx[i*3+2]=szz[j];
  }
}

// ---------------- ball query: first K in-radius indices (ascending) + argmin fallback ----
template<int NSRC,int SQ,int K>
__global__ __launch_bounds__(64) void ball_query(const float* __restrict__ qxyz, const float* __restrict__ sxyz,
                                                 int* __restrict__ gidx, float r2)
{
  __shared__ float4 tile[1024];
  const int z = blockIdx.y, tid = threadIdx.x;
  const int s = blockIdx.x*64 + tid;
  const float* q = qxyz + (z*SQ+s)*3;
  const float qx=q[0],qy=q[1],qz=q[2];
  const float qq=nrm3(qx,qy,qz);
  int cnt=0, first=0, amin=0; float dmin=3.0e38f;
  int* out = gidx + (z*SQ+s)*K;
  for (int t0=0;t0<NSRC;t0+=1024){
    __syncthreads();
    for (int i=tid;i<1024;i+=64){
      const float* p = sxyz + (z*NSRC+t0+i)*3;
      float x=p[0],y=p[1],w=p[2];
      tile[i]=make_float4(x,y,w,nrm3(x,y,w));
    }
    __syncthreads();
    for (int jj=0;jj<1024;jj++){
      float4 p = tile[jj];
      float dot=dot3(qx,qy,qz,p.x,p.y,p.z);
      float d=(qq+p.w)-2.0f*dot;
      const int j = t0+jj;
      if (d < dmin){ dmin=d; amin=j; }
      if (d <= r2 && cnt < K){ if(cnt==0) first=j; out[cnt]=j; cnt++; }
    }
  }
  const int fill = (cnt==0)? amin : first;
  for (int c=cnt;c<K;c++) out[c]=fill;
}

// ---------------- set-abstraction conv passes ----------------
template<int S,int K,int CF,int C1,int C2,int NSRC,int PASS>
__global__ __launch_bounds__(256) void sa_pass(
    const float* __restrict__ srcxyz, const float* __restrict__ srcfea,
    const float* __restrict__ qxyz, const int* __restrict__ gidx,
    const float* __restrict__ w0, const float* __restrict__ g0, const float* __restrict__ b0,
    const float* __restrict__ w1, const float* __restrict__ g1v, const float* __restrict__ b1v,
    float* __restrict__ stats, int offA, int offB, float cnt0, float cnt1,
    float* __restrict__ outp)
{
  constexpr int CIN = 3+CF;
  __shared__ float w0l[C1*CIN];
  __shared__ float w1l[PASS>=2 ? C2*C1 : 1];
  __shared__ float sc0[C1], bi0[C1];
  __shared__ float sc1[C2], bi1[C2];
  __shared__ float sred[4][128];
  const int z = blockIdx.y, pipe = z>>1, tid = threadIdx.x;
  float* stA = stats + pipe*1024 + offA;
  float* stB = stats + pipe*1024 + offB;
  for (int i=tid;i<C1*CIN;i+=256) w0l[i]=w0[i];
  if (PASS>=2){
    for (int i=tid;i<C2*C1;i+=256) w1l[i]=w1[i];
    if (tid<C1){
      float m = stA[tid]/cnt0;
      float var = stA[C1+tid]/cnt0 - m*m;
      float rs = 1.0f/sqrtf(var+1e-5f);
      float sc = rs*g0[tid];
      sc0[tid]=sc; bi0[tid]=b0[tid]-m*sc;
    }
  }
  if (PASS==3 && tid<C2){
    float m = stB[tid]/cnt1;
    float var = stB[C2+tid]/cnt1 - m*m;
    float rs = 1.0f/sqrtf(var+1e-5f);
    float sc = rs*g1v[tid];
    sc1[tid]=sc; bi1[tid]=b1v[tid]-m*sc;
  }
  __syncthreads();
  const int item = blockIdx.x*256+tid;
  const int s = item/K;
  const int j = gidx[(z*S+s)*K + (item%K)];
  const float* q = qxyz + (z*S+s)*3;
  const float* p = srcxyz + (z*NSRC+j)*3;
  float f[CIN];
  f[0]=p[0]-q[0]; f[1]=p[1]-q[1]; f[2]=p[2]-q[2];
  const float* fe = srcfea + (z*NSRC+j)*CF;
  #pragma unroll
  for (int c=0;c<CF;c++) f[3+c]=fe[c];
  float h1[C1];
  #pragma unroll
  for (int o=0;o<C1;o++){
    float a=0.f;
    #pragma unroll
    for (int c=0;c<CIN;c++) a = fmaf(w0l[o*CIN+c], f[c], a);
    h1[o]=a;
  }
  if (PASS==1){ stats_accum<C1>(h1, stA, sred); return; }
  float f2v[C1];
  #pragma unroll
  for (int o=0;o<C1;o++) f2v[o]=fmaxf(fmaf(h1[o],sc0[o],bi0[o]), 0.f);
  float h2[C2];
  #pragma unroll
  for (int o=0;o<C2;o++){
    float a=0.f;
    #pragma unroll
    for (int c=0;c<C1;c++) a = fmaf(w1l[o*C1+c], f2v[c], a);
    h2[o]=a;
  }
  if (PASS==2){ stats_accum<C2>(h2, stB, sred); return; }
  #pragma unroll
  for (int o=0;o<C2;o++) h2[o]=fmaxf(fmaf(h2[o],sc1[o],bi1[o]), 0.f);
  #pragma unroll
  for (int msk=1; msk<K; msk<<=1){
    #pragma unroll
    for (int o=0;o<C2;o++) h2[o]=fmaxf(h2[o], __shfl_xor(h2[o], msk, 64));
  }
  if ((tid & (K-1))==0){
    float* op = outp + (z*S+s)*C2;
    #pragma unroll
    for (int o=0;o<C2;o++) op[o]=h2[o];
  }
}

// ---------------- upconv: stable 8-NN (64-thread blocks, order-preserving) ----------------
__global__ __launch_bounds__(64) void up_top8(const float* __restrict__ nx1, const float* __restrict__ nx2,
                                              int* __restrict__ uidx)
{
  __shared__ float4 tile[1024];
  const int z=blockIdx.y, tid=threadIdx.x;
  const int s=blockIdx.x*64+tid;
  const float* q = nx1 + (z*4096+s)*3;
  const float qx=q[0],qy=q[1],qz=q[2];
  const float qq=nrm3(qx,qy,qz);
  for (int i=tid;i<1024;i+=64){
    const float* p = nx2 + (z*1024+i)*3;
    float x=p[0],y=p[1],w=p[2];
    tile[i]=make_float4(x,y,w,nrm3(x,y,w));
  }
  __syncthreads();
  float d[8]; int id[8];
  #pragma unroll
  for (int r=0;r<8;r++){ d[r]=3e38f; id[r]=0; }
  for (int j=0;j<1024;j++){
    float4 p=tile[j];
    float dt=dot3(qx,qy,qz,p.x,p.y,p.z);
    float dd=(qq+p.w)-2.0f*dt;
    if (dd<d[7]){
      d[7]=dd; id[7]=j;
      #pragma unroll
      for (int r=7;r>0;r--){
        if (d[r]<d[r-1]){ float td=d[r-1]; d[r-1]=d[r]; d[r]=td; int ti=id[r-1]; id[r-1]=id[r]; id[r]=ti; }
      }
    }
  }
  int* o = uidx + (z*4096+s)*8;
  #pragma unroll
  for (int r=0;r<8;r++) o[r]=id[r];
}

template<int PASS>
__global__ __launch_bounds__(256) void up_pass(
    const float* __restrict__ nx1, const float* __restrict__ nx2,
    const float* __restrict__ l2f, const float* __restrict__ l1f,
    const int* __restrict__ uidx,
    const float* __restrict__ w1, const float* __restrict__ g1v, const float* __restrict__ b1v,
    const float* __restrict__ w2,
    float* __restrict__ stats, float* __restrict__ uh2)
{
  __shared__ float w1l[32*67];
  __shared__ float w2l[PASS==2?32*64:1];
  __shared__ float sc0[32], bi0[32];
  __shared__ float sred[4][128];
  const int z=blockIdx.y, pipe=z>>1, tid=threadIdx.x;
  float* stU1 = stats + pipe*1024 + ST_U1;
  float* stU2 = stats + pipe*1024 + ST_U2;
  for (int i=tid;i<32*67;i+=256) w1l[i]=w1[i];
  if (PASS==2){
    for (int i=tid;i<32*64;i+=256) w2l[i]=w2[i];
    if (tid<32){
      float m=stU1[tid]/65536.f;
      float var=stU1[32+tid]/65536.f - m*m;
      float rs=1.0f/sqrtf(var+1e-5f);
      float sc=rs*g1v[tid];
      sc0[tid]=sc; bi0[tid]=b1v[tid]-m*sc;
    }
  }
  __syncthreads();
  const int item = blockIdx.x*256+tid;
  const int s = item>>3, k = item&7;
  const int j = uidx[(z*4096+s)*8+k];
  float f67[67];
  const float* fe = l2f + (z*1024+j)*64;
  #pragma unroll
  for (int c=0;c<64;c++) f67[c]=fe[c];
  const float* pp = nx2 + (z*1024+j)*3;
  const float* qv = nx1 + (z*4096+s)*3;
  f67[64]=pp[0]-qv[0]; f67[65]=pp[1]-qv[1]; f67[66]=pp[2]-qv[2];
  float h[32];
  #pragma unroll
  for (int o=0;o<32;o++){
    float a=0.f;
    #pragma unroll
    for (int c=0;c<67;c++) a=fmaf(w1l[o*67+c], f67[c], a);
    h[o]=a;
  }
  if (PASS==1){ stats_accum<32>(h, stU1, sred); return; }
  #pragma unroll
  for (int o=0;o<32;o++) h[o]=fmaxf(fmaf(h[o],sc0[o],bi0[o]),0.f);
  #pragma unroll
  for (int msk=1; msk<8; msk<<=1){
    #pragma unroll
    for (int o=0;o<32;o++) h[o]=fmaxf(h[o], __shfl_xor(h[o],msk,64));
  }
  float h2[32];
  if (k==0){
    const float* l1 = l1f + (z*4096+s)*32;
    #pragma unroll
    for (int o=0;o<32;o++){
      float a=0.f;
      #pragma unroll
      for (int c=0;c<32;c++) a=fmaf(w2l[o*64+c], h[c], a);
      #pragma unroll
      for (int c=0;c<32;c++) a=fmaf(w2l[o*64+32+c], l1[c], a);
      h2[o]=a;
    }
    float* up = uh2 + (z*4096+s)*32;
    #pragma unroll
    for (int o=0;o<32;o++) up[o]=h2[o];
  } else {
    #pragma unroll
    for (int o=0;o<32;o++) h2[o]=0.f;
  }
  stats_accum<32>(h2, stU2, sred);
}

__global__ __launch_bounds__(256) void up_norm(const float* __restrict__ uh2, const float* __restrict__ g,
                                               const float* __restrict__ b, const float* __restrict__ stats,
                                               float* __restrict__ l1n)
{
  const int i = blockIdx.x*256+threadIdx.x;   // < 4*4096*32
  const int z = i>>17, pipe = z>>1, c = i&31;
  const float* st = stats + pipe*1024 + ST_U2;
  float m = st[c]/8192.f;
  float var = st[32+c]/8192.f - m*m;
  float rs = 1.0f/sqrtf(var+1e-5f);
  float sc = rs*g[c];
  float bi = b[c]-m*sc;
  l1n[i]=fmaxf(fmaf(uh2[i],sc,bi),0.f);
}

// ---------------- feature propagation: 3-NN interpolate + conv ----------------
__global__ __launch_bounds__(256) void fp_kern(
  const float* __restrict__ xyzf, const float* __restrict__ feaf,
  const float* __restrict__ nx1, const float* __restrict__ l1n,
  const float* __restrict__ fpw, float* __restrict__ stats, float* __restrict__ h3)
{
  __shared__ float4 tile[2048];
  __shared__ float wl[32*42];
  __shared__ float sred[4][128];
  const int z=blockIdx.y, pipe=z>>1, tid=threadIdx.x;
  for (int i=tid;i<32*42;i+=256) wl[i]=fpw[i];
  const int n = blockIdx.x*256+tid;
  const float* q = xyzf + (z*8192+n)*3;
  const float qx=q[0],qy=q[1],qz=q[2];
  const float qq2=nrm3(qx,qy,qz);
  float d0=3e38f,d1=3e38f,d2=3e38f; int i0=0,i1=0,i2=0;
  for (int t0=0;t0<4096;t0+=2048){
    __syncthreads();
    for (int i=tid;i<2048;i+=256){
      const float* p = nx1 + (z*4096+t0+i)*3;
      float x=p[0],y=p[1],w=p[2];
      tile[i]=make_float4(x,y,w,nrm3(x,y,w));
    }
    __syncthreads();
    for (int jj=0;jj<2048;jj++){
      float4 p=tile[jj];
      float dt=dot3(qx,qy,qz,p.x,p.y,p.z);
      float d=(qq2+p.w)-2.0f*dt;
      if (d<d2){
        d2=d; i2=t0+jj;
        if (d2<d1){ float td=d1; d1=d2; d2=td; int ti=i1; i1=i2; i2=ti; }
        if (d1<d0){ float td=d0; d0=d1; d1=td; int ti=i0; i0=i1; i1=ti; }
      }
    }
  }
  d0=fmaxf(d0,1e-10f); d1=fmaxf(d1,1e-10f); d2=fmaxf(d2,1e-10f);
  float w0=1.0f/d0, w1=1.0f/d1, w2=1.0f/d2;
  float wsum=(w0+w1)+w2;
  w0/=wsum; w1/=wsum; w2/=wsum;
  const float* A = l1n + (z*4096+i0)*32;
  const float* B = l1n + (z*4096+i1)*32;
  const float* C = l1n + (z*4096+i2)*32;
  float f[42];
  #pragma unroll
  for (int c=0;c<32;c++) f[c]=fmaf(C[c],w2, fmaf(B[c],w1, A[c]*w0));
  const float* fe = feaf + (z*8192+n)*10;
  #pragma unroll
  for (int c=0;c<10;c++) f[32+c]=fe[c];
  float h[32];
  #pragma unroll
  for (int o=0;o<32;o++){
    float a=0.f;
    #pragma unroll
    for (int c=0;c<42;c++) a=fmaf(wl[o*42+c], f[c], a);
    h[o]=a;
    h3[(z*8192+n)*32+o]=a;
  }
  stats_accum<32>(h, stats + pipe*1024 + ST_FP, sred);
}

__global__ __launch_bounds__(256) void fp_post(const float* __restrict__ h3, const float* __restrict__ g,
                                               const float* __restrict__ b, float* __restrict__ stats,
                                               float* __restrict__ l0n)
{
  __shared__ float sc[32], bi[32];
  __shared__ float sred[4][128];
  const int tid=threadIdx.x;
  const int row = blockIdx.x*256+tid;     // 32768
  const int pipe = row>>14;
  float* stF = stats + pipe*1024 + ST_FP;
  float* stB = stats + pipe*1024 + ST_BN1;
  if (tid<32){
    float m=stF[tid]/16384.f;
    float var=stF[32+tid]/16384.f-m*m;
    float rs=1.0f/sqrtf(var+1e-5f);
    float s=rs*g[tid];
    sc[tid]=s; bi[tid]=b[tid]-m*s;
  }
  __syncthreads();
  float x[32];
  #pragma unroll
  for (int c=0;c<32;c++){ x[c]=fmaxf(fmaf(h3[row*32+c],sc[c],bi[c]),0.f); l0n[row*32+c]=x[c]; }
  stats_accum<32>(x, stB, sred);
}

__global__ __launch_bounds__(256) void final_kern(
  const float* __restrict__ l0n, const float* __restrict__ g, const float* __restrict__ b,
  const float* __restrict__ cw, const float* __restrict__ cb,
  const float* __restrict__ p1, const float* __restrict__ p2,
  const float* __restrict__ stats, float* __restrict__ out)
{
  __shared__ float sc[32], bi[32], wl[512], bl[16];
  const int tid=threadIdx.x;
  const int row = blockIdx.x*256+tid;
  const int z=row>>13, pipe=z>>1, bb=z&1, n=row&8191;
  const float* st = stats + pipe*1024 + ST_BN1;
  if (tid<32){
    float m=st[tid]/16384.f;
    float var=st[32+tid]/16384.f-m*m;
    float rs=1.0f/sqrtf(var+1e-5f);
    float s=rs*g[tid];
    sc[tid]=s; bi[tid]=b[tid]-m*s;
  }
  for (int i=tid;i<512;i+=256) wl[i]=cw[i];
  if (tid<16) bl[tid]=cb[tid];
  __syncthreads();
  float x[32];
  #pragma unroll
  for (int c=0;c<32;c++) x[c]=fmaxf(fmaf(l0n[row*32+c],sc[c],bi[c]),0.f);
  float* o = out + row*19;
  const float* ps = (pipe?p2:p1) + (bb*8192+n)*3;
  o[0]=ps[0]; o[1]=ps[1]; o[2]=ps[2];
  #pragma unroll
  for (int oo=0;oo<16;oo++){
    float a=0.f;
    #pragma unroll
    for (int c=0;c<32;c++) a=fmaf(wl[oo*32+c],x[c],a);
    o[3+oo]=a+bl[oo];
  }
}

// ---------------- host ----------------
extern "C" void kernel_launch(void* const* d_in, const int* in_sizes, int n_in,
                              void* d_out, int out_size, void* d_ws, size_t ws_size,
                              hipStream_t stream)
{
  (void)in_sizes; (void)n_in; (void)out_size; (void)ws_size;
  const float* p1 = (const float*)d_in[0];
  const float* f1 = (const float*)d_in[1];
  const float* p2 = (const float*)d_in[2];
  const float* f2 = (const float*)d_in[3];
  const float *sa1_w0=(const float*)d_in[4], *sa1_g0=(const float*)d_in[5], *sa1_b0=(const float*)d_in[6];
  const float *sa1_w1=(const float*)d_in[7], *sa1_g1=(const float*)d_in[8], *sa1_b1=(const float*)d_in[9];
  const float *sa2_w0=(const float*)d_in[10],*sa2_g0=(const float*)d_in[11],*sa2_b0=(const float*)d_in[12];
  const float *sa2_w1=(const float*)d_in[13],*sa2_g1=(const float*)d_in[14],*sa2_b1=(const float*)d_in[15];
  const float *su1_w1=(const float*)d_in[16],*su1_g1=(const float*)d_in[17],*su1_b1=(const float*)d_in[18];
  const float *su1_w2=(const float*)d_in[19],*su1_g2=(const float*)d_in[20],*su1_b2=(const float*)d_in[21];
  const float *fp_w=(const float*)d_in[22], *fp_g=(const float*)d_in[23], *fp_b=(const float*)d_in[24];
  const float *bn1_g=(const float*)d_in[25],*bn1_b=(const float*)d_in[26];
  const float *conv2_w=(const float*)d_in[27],*conv2_b=(const float*)d_in[28];
  float* wsf=(float*)d_ws; int* wsi=(int*)d_ws;
  float* xyzf=wsf+OFF_XYZF; float* feaf=wsf+OFF_FEAF;
  float* nx1=wsf+OFF_NX1; float* l1f=wsf+OFF_L1F;
  float* nx2=wsf+OFF_NX2; float* l2f=wsf+OFF_L2F;
  float* uh2=wsf+OFF_UH2; float* l1n=wsf+OFF_L1N;
  float* h3=wsf+OFF_H3; float* l0n=wsf+OFF_L0N;
  float* stats=wsf+OFF_STATS;
  int* gidx1=wsi+OFF_GIDX1; int* gidx2=wsi+OFF_GIDX2; int* uidx=wsi+OFF_UIDX;
  // radius*radius is computed in Python f64 then demoted to f32
  const float R2A=(float)(0.1*0.1), R2B=(float)(0.2*0.2);

  (void)hipMemsetAsync(stats, 0, 2048*sizeof(float), stream);
  prep<<<128,256,0,stream>>>(p1,f1,p2,f2,xyzf,feaf);
  fps_kernel<8192,4096,512><<<4,512,0,stream>>>(xyzf, nx1);
  ball_query<8192,4096,16><<<dim3(64,4),64,0,stream>>>(nx1, xyzf, gidx1, R2A);
  sa_pass<4096,16,10,16,32,8192,1><<<dim3(256,4),256,0,stream>>>(xyzf,feaf,nx1,gidx1,
      sa1_w0,sa1_g0,sa1_b0,sa1_w1,sa1_g1,sa1_b1, stats,ST_SA1A,ST_SA1B,131072.f,131072.f, l1f);
  sa_pass<4096,16,10,16,32,8192,2><<<dim3(256,4),256,0,stream>>>(xyzf,feaf,nx1,gidx1,
      sa1_w0,sa1_g0,sa1_b0,sa1_w1,sa1_g1,sa1_b1, stats,ST_SA1A,ST_SA1B,131072.f,131072.f, l1f);
  sa_pass<4096,16,10,16,32,8192,3><<<dim3(256,4),256,0,stream>>>(xyzf,feaf,nx1,gidx1,
      sa1_w0,sa1_g0,sa1_b0,sa1_w1,sa1_g1,sa1_b1, stats,ST_SA1A,ST_SA1B,131072.f,131072.f, l1f);
  fps_kernel<4096,1024,512><<<4,512,0,stream>>>(nx1, nx2);
  ball_query<4096,1024,16><<<dim3(16,4),64,0,stream>>>(nx2, nx1, gidx2, R2B);
  sa_pass<1024,16,32,32,64,4096,1><<<dim3(64,4),256,0,stream>>>(nx1,l1f,nx2,gidx2,
      sa2_w0,sa2_g0,sa2_b0,sa2_w1,sa2_g1,sa2_b1, stats,ST_SA2A,ST_SA2B,32768.f,32768.f, l2f);
  sa_pass<1024,16,32,32,64,4096,2><<<dim3(64,4),256,0,stream>>>(nx1,l1f,nx2,gidx2,
      sa2_w0,sa2_g0,sa2_b0,sa2_w1,sa2_g1,sa2_b1, stats,ST_SA2A,ST_SA2B,32768.f,32768.f, l2f);
  sa_pass<1024,16,32,32,64,4096,3><<<dim3(64,4),256,0,stream>>>(nx1,l1f,nx2,gidx2,
      sa2_w0,sa2_g0,sa2_b0,sa2_w1,sa2_g1,sa2_b1, stats,ST_SA2A,ST_SA2B,32768.f,32768.f, l2f);
  up_top8<<<dim3(64,4),64,0,stream>>>(nx1,nx2,uidx);
  up_pass<1><<<dim3(128,4),256,0,stream>>>(nx1,nx2,l2f,l1f,uidx,su1_w1,su1_g1,su1_b1,su1_w2,stats,uh2);
  up_pass<2><<<dim3(128,4),256,0,stream>>>(nx1,nx2,l2f,l1f,uidx,su1_w1,su1_g1,su1_b1,su1_w2,stats,uh2);
  up_norm<<<2048,256,0,stream>>>(uh2,su1_g2,su1_b2,stats,l1n);
  fp_kern<<<dim3(32,4),256,0,stream>>>(xyzf,feaf,nx1,l1n,fp_w,stats,h3);
  fp_post<<<128,256,0,stream>>>(h3,fp_g,fp_b,stats,l0n);
  final_kern<<<128,256,0,stream>>>(l0n,bn1_g,bn1_b,conv2_w,conv2_b,p1,p2,stats,(float*)d_out);
}